// Round 1
// baseline (186.116 us; speedup 1.0000x reference)
//
#include <hip/hip_runtime.h>

// Problem constants
#define BATCH 8
#define SEQ   512
#define EMB   1024
#define NH    16
#define HD    64
// dist table rows = 2*512-1 = 1023 (+1 zero pad row)

typedef __bf16 bf16x8 __attribute__((ext_vector_type(8)));
typedef float  f32x4  __attribute__((ext_vector_type(4)));

__device__ __forceinline__ unsigned short f2bf(float f){
  union { float f; unsigned u; } v; v.f = f;
  unsigned r = v.u + 0x7FFFu + ((v.u >> 16) & 1u);
  return (unsigned short)(r >> 16);
}
__device__ __forceinline__ float bf2f(unsigned short s){
  union { unsigned u; float f; } v; v.u = ((unsigned)s) << 16;
  return v.f;
}

// XOR-swizzle helpers for LDS tiles with rows of 64 bf16 (128 B rows).
// chunk = 16B unit within row (0..7).  byte ^= (row&7)<<4  (G4 fix).
__device__ __forceinline__ int swzc(int row, int chunk){
  return row * 128 + (((chunk ^ (row & 7)) & 7) << 4);
}
__device__ __forceinline__ int swz2(int row, int col){ // col = bf16 element 0..63
  return row * 128 + ((((col >> 3) ^ (row & 7)) & 7) << 4) + ((col & 7) << 1);
}

// ---------------- prep kernels ----------------
__global__ void k_conv_hidden(const float* __restrict__ in, unsigned short* __restrict__ out){
  int i = (blockIdx.x * 256 + threadIdx.x) * 4;
  float4 v = *(const float4*)(in + i);
  ushort4 o; o.x = f2bf(v.x); o.y = f2bf(v.y); o.z = f2bf(v.z); o.w = f2bf(v.w);
  *(ushort4*)(out + i) = o;
}

__global__ void k_wt(const float* __restrict__ W, unsigned short* __restrict__ WT){
  __shared__ float t[32][33];
  int n0 = blockIdx.x * 32, k0 = blockIdx.y * 32;
  int tx = threadIdx.x, ty = threadIdx.y;
#pragma unroll
  for (int i = 0; i < 4; i++)
    t[ty + 8*i][tx] = W[(k0 + ty + 8*i) * EMB + n0 + tx];
  __syncthreads();
#pragma unroll
  for (int i = 0; i < 4; i++)
    WT[(n0 + ty + 8*i) * EMB + k0 + tx] = f2bf(t[tx][ty + 8*i]);
}

__global__ void k_dist(const float* __restrict__ in, unsigned short* __restrict__ out){
  int i = blockIdx.x * 256 + threadIdx.x;          // 1024*64 total
  out[i] = (i < 1023 * 64) ? f2bf(in[i]) : (unsigned short)0;
}

// ---------------- QKV projection GEMM ----------------
// C[m,n] = sum_k A[m,k] * W[k,n] + bias[n];  A bf16 [4096][1024], BT = W^T bf16 [1024][1024]
// mode 0: out[b,h,s,d] (Q,K)   mode 1: out[b,h,d,s] (V transposed)
__global__ __launch_bounds__(256) void k_gemm(const unsigned short* __restrict__ A,
                                              const unsigned short* __restrict__ BT,
                                              const float* __restrict__ bias,
                                              unsigned short* __restrict__ out, int mode){
  __shared__ __align__(16) unsigned char sA[128 * 128];
  __shared__ __align__(16) unsigned char sB[128 * 128];
  int m0 = blockIdx.y * 128, n0 = blockIdx.x * 128;
  int t = threadIdx.x, w = t >> 6, lane = t & 63, g = lane >> 4, lr = lane & 15;
  int rowbase = (w >> 1) * 64, colbase = (w & 1) * 64;
  f32x4 acc[4][4] = {};
  for (int k0 = 0; k0 < EMB; k0 += 64){
    __syncthreads();
#pragma unroll
    for (int i = 0; i < 4; i++){
      int lin = t + 256*i, row = lin >> 3, c = lin & 7;
      *(uint4*)(sA + swzc(row, c)) = *(const uint4*)(A  + (m0 + row) * EMB + k0 + c*8);
      *(uint4*)(sB + swzc(row, c)) = *(const uint4*)(BT + (n0 + row) * EMB + k0 + c*8);
    }
    __syncthreads();
#pragma unroll
    for (int kk = 0; kk < 2; kk++){
      bf16x8 af[4], bfv[4];
#pragma unroll
      for (int i = 0; i < 4; i++) af[i]  = *(const bf16x8*)(sA + swzc(rowbase + 16*i + lr, kk*4 + g));
#pragma unroll
      for (int j = 0; j < 4; j++) bfv[j] = *(const bf16x8*)(sB + swzc(colbase + 16*j + lr, kk*4 + g));
#pragma unroll
      for (int i = 0; i < 4; i++)
#pragma unroll
        for (int j = 0; j < 4; j++)
          acc[i][j] = __builtin_amdgcn_mfma_f32_16x16x32_bf16(af[i], bfv[j], acc[i][j], 0, 0, 0);
    }
  }
#pragma unroll
  for (int i = 0; i < 4; i++)
#pragma unroll
    for (int j = 0; j < 4; j++)
#pragma unroll
      for (int r = 0; r < 4; r++){
        int m = m0 + rowbase + 16*i + 4*g + r;
        int n = n0 + colbase + 16*j + lr;
        float val = acc[i][j][r] + bias[n];
        int b = m >> 9, s = m & 511, h = n >> 6, d = n & 63;
        int idx = (mode == 0) ? (((b*NH + h)*SEQ + s)*HD + d)
                              : (((b*NH + h)*HD + d)*SEQ + s);
        out[idx] = f2bf(val);
      }
}

// ---------------- fused rel-pos attention ----------------
// grid: 1024 = B*H*(S/64); block 256 = 4 waves x 16 l-rows each
__global__ __launch_bounds__(256) void k_attn(const unsigned short* __restrict__ qb,
                                              const unsigned short* __restrict__ kb,
                                              const unsigned short* __restrict__ vtb,
                                              const unsigned short* __restrict__ distb,
                                              const float* __restrict__ mask,
                                              float* __restrict__ out){
  __shared__ __align__(16) unsigned char sQ[64 * 128];
  __shared__ __align__(16) unsigned char sK[64 * 128];
  __shared__ __align__(16) unsigned char sV[64 * 128];   // V^T tile: [d][r]
  __shared__ __align__(16) unsigned char sPE[128 * 128]; // pe band: 128 rows x 64 bf16
  __shared__ __align__(16) unsigned char sAB[64 * 256];  // Aband [64][128] bf16; P overlays per-wave stripe
  __shared__ __align__(16) unsigned char sBB[64 * 256];  // Bband [64][128] bf16
  __shared__ float sM[64];

  int wg = blockIdx.x;
  int lt = wg & 7, h = (wg >> 3) & 15, b = wg >> 7;
  int L0 = lt * 64;
  int bh = b * NH + h;
  int t = threadIdx.x, w = t >> 6, lane = t & 63, g = lane >> 4, lr = lane & 15;

  { // stage Q tile rows L0..L0+63
    const unsigned short* src = qb + (bh * SEQ + L0) * HD;
#pragma unroll
    for (int i = 0; i < 2; i++){
      int lin = t + 256*i, row = lin >> 3, c = lin & 7;
      *(uint4*)(sQ + swzc(row, c)) = *(const uint4*)(src + row * HD + c*8);
    }
  }

  f32x4 o[4] = {};
  float mrun[4], srun[4];
#pragma unroll
  for (int r = 0; r < 4; r++){ mrun[r] = -1e30f; srun[r] = 0.f; }

  for (int rt = 0; rt < 8; rt++){
    int R0 = rt * 64;
    int jb = L0 - R0 + 448;        // pe band start row (0..896), 128 rows staged
    __syncthreads();
    { // stage K tile, V^T tile, PE band, mask
      const unsigned short* ks = kb  + (bh * SEQ + R0) * HD;
      const unsigned short* vs = vtb + bh * HD * SEQ + R0;
#pragma unroll
      for (int i = 0; i < 2; i++){
        int lin = t + 256*i, row = lin >> 3, c = lin & 7;
        *(uint4*)(sK + swzc(row, c)) = *(const uint4*)(ks + row * HD  + c*8);
        *(uint4*)(sV + swzc(row, c)) = *(const uint4*)(vs + row * SEQ + c*8);
      }
      const unsigned short* ps = distb + jb * HD;
#pragma unroll
      for (int i = 0; i < 4; i++){
        int lin = t + 256*i, row = lin >> 3, c = lin & 7;
        *(uint4*)(sPE + swzc(row, c)) = *(const uint4*)(ps + row * HD + c*8);
      }
      if (t < 64) sM[t] = mask[b * SEQ + R0 + t];
    }
    __syncthreads();

    { // band matmuls: wave w computes 16-row stripes of Aband (q.pe) and Bband (k.pe)
      bf16x8 aq[2], ak[2];
#pragma unroll
      for (int kk = 0; kk < 2; kk++){
        aq[kk] = *(const bf16x8*)(sQ + swzc(16*w + lr, kk*4 + g));
        ak[kk] = *(const bf16x8*)(sK + swzc(16*w + lr, kk*4 + g));
      }
#pragma unroll
      for (int jt = 0; jt < 8; jt++){
        bf16x8 pe0 = *(const bf16x8*)(sPE + swzc(16*jt + lr, g));
        bf16x8 pe1 = *(const bf16x8*)(sPE + swzc(16*jt + lr, 4 + g));
        f32x4 accA = {}, accB = {};
        accA = __builtin_amdgcn_mfma_f32_16x16x32_bf16(aq[0], pe0, accA, 0, 0, 0);
        accA = __builtin_amdgcn_mfma_f32_16x16x32_bf16(aq[1], pe1, accA, 0, 0, 0);
        accB = __builtin_amdgcn_mfma_f32_16x16x32_bf16(ak[0], pe0, accB, 0, 0, 0);
        accB = __builtin_amdgcn_mfma_f32_16x16x32_bf16(ak[1], pe1, accB, 0, 0, 0);
#pragma unroll
        for (int r = 0; r < 4; r++){
          int rowloc = 4*g + r, col = 16*jt + lr;
          *(unsigned short*)(sAB + (16*w + rowloc) * 256 + col * 2) = f2bf(accA[r]);
          *(unsigned short*)(sBB + (16*w + rowloc) * 256 + col * 2) = f2bf(accB[r]);
        }
      }
    }
    __syncthreads();

    // QK^T scores + band adds + scale + mask
    f32x4 sc[4];
    {
      bf16x8 aq[2];
#pragma unroll
      for (int kk = 0; kk < 2; kk++)
        aq[kk] = *(const bf16x8*)(sQ + swzc(16*w + lr, kk*4 + g));
#pragma unroll
      for (int f = 0; f < 4; f++){
        f32x4 a = {};
#pragma unroll
        for (int kk = 0; kk < 2; kk++){
          bf16x8 bk_ = *(const bf16x8*)(sK + swzc(16*f + lr, kk*4 + g));
          a = __builtin_amdgcn_mfma_f32_16x16x32_bf16(aq[kk], bk_, a, 0, 0, 0);
        }
#pragma unroll
        for (int r = 0; r < 4; r++){
          int lloc = 16*w + 4*g + r;
          int rloc = 16*f + lr;
          int jj = lloc - rloc + 63;   // 0..126
          float ab = bf2f(*(const unsigned short*)(sAB + lloc * 256 + jj * 2));
          float bb = bf2f(*(const unsigned short*)(sBB + rloc * 256 + jj * 2));
          a[r] = (a[r] + ab + bb) * 0.125f + sM[rloc];
        }
        sc[f] = a;
      }
    }

    // online softmax (rows = 4*g+r within wave stripe; 16 lanes of group g hold 16 cols)
    float fac[4];
#pragma unroll
    for (int r = 0; r < 4; r++){
      float tm = fmaxf(fmaxf(sc[0][r], sc[1][r]), fmaxf(sc[2][r], sc[3][r]));
#pragma unroll
      for (int x = 1; x < 16; x <<= 1) tm = fmaxf(tm, __shfl_xor(tm, x, 16));
      float mnew = fmaxf(mrun[r], tm);
      float fr = expf(mrun[r] - mnew);
      float ps = 0.f;
#pragma unroll
      for (int f = 0; f < 4; f++){ float p = expf(sc[f][r] - mnew); sc[f][r] = p; ps += p; }
#pragma unroll
      for (int x = 1; x < 16; x <<= 1) ps += __shfl_xor(ps, x, 16);
      srun[r] = srun[r] * fr + ps;
      mrun[r] = mnew;
      fac[r]  = fr;
    }
#pragma unroll
    for (int df = 0; df < 4; df++)
#pragma unroll
      for (int r = 0; r < 4; r++) o[df][r] *= fac[r];

    // write P (bf16) into this wave's private stripe (overlays Aband region; same-wave ordering)
    unsigned char* P = sAB + w * 4096;
#pragma unroll
    for (int f = 0; f < 4; f++)
#pragma unroll
      for (int r = 0; r < 4; r++)
        *(unsigned short*)(P + swz2(4*g + r, 16*f + lr)) = f2bf(sc[f][r]);

    // PV: O[16 l x 64 d] += P[16 l x 64 r] * V[64 r x 64 d]
#pragma unroll
    for (int kk = 0; kk < 2; kk++){
      bf16x8 pf = *(const bf16x8*)(P + swzc(lr, kk*4 + g));
#pragma unroll
      for (int df = 0; df < 4; df++){
        bf16x8 vf = *(const bf16x8*)(sV + swzc(16*df + lr, kk*4 + g));
        o[df] = __builtin_amdgcn_mfma_f32_16x16x32_bf16(pf, vf, o[df], 0, 0, 0);
      }
    }
  }

  // epilogue: normalize and write out[b, l, h*64+d] (f32)
#pragma unroll
  for (int df = 0; df < 4; df++)
#pragma unroll
    for (int r = 0; r < 4; r++){
      int l = L0 + 16*w + 4*g + r;
      float val = o[df][r] / srun[r];
      out[(b * SEQ + l) * EMB + h * HD + 16*df + lr] = val;
    }
}

extern "C" void kernel_launch(void* const* d_in, const int* in_sizes, int n_in,
                              void* d_out, int out_size, void* d_ws, size_t ws_size,
                              hipStream_t stream) {
  (void)in_sizes; (void)n_in; (void)out_size; (void)ws_size;
  const float* hid  = (const float*)d_in[0];
  const float* mask = (const float*)d_in[1];
  const float* Wq   = (const float*)d_in[2];
  const float* bq   = (const float*)d_in[3];
  const float* Wk   = (const float*)d_in[4];
  const float* bk   = (const float*)d_in[5];
  const float* Wv   = (const float*)d_in[6];
  const float* bv   = (const float*)d_in[7];
  const float* dist = (const float*)d_in[8];
  float* out = (float*)d_out;

  unsigned char* ws = (unsigned char*)d_ws;
  unsigned short* hidb  = (unsigned short*)ws;                    // 4096*1024 bf16 = 8 MB
  unsigned short* wqt   = hidb + 4096 * 1024;                     // 2 MB each
  unsigned short* wkt   = wqt  + 1024 * 1024;
  unsigned short* wvt   = wkt  + 1024 * 1024;
  unsigned short* distb = wvt  + 1024 * 1024;                     // 1024*64 bf16 (padded)
  unsigned short* qb    = distb + 1024 * 64;                      // [B,H,S,D] bf16, 8 MB
  unsigned short* kb    = qb + BATCH * NH * SEQ * HD;
  unsigned short* vtb   = kb + BATCH * NH * SEQ * HD;             // [B,H,D,S] bf16

  k_conv_hidden<<<4096, 256, 0, stream>>>(hid, hidb);
  k_wt<<<dim3(32, 32), dim3(32, 8), 0, stream>>>(Wq, wqt);
  k_wt<<<dim3(32, 32), dim3(32, 8), 0, stream>>>(Wk, wkt);
  k_wt<<<dim3(32, 32), dim3(32, 8), 0, stream>>>(Wv, wvt);
  k_dist<<<256, 256, 0, stream>>>(dist, distb);

  k_gemm<<<dim3(8, 32), 256, 0, stream>>>(hidb, wqt, bq, qb, 0);
  k_gemm<<<dim3(8, 32), 256, 0, stream>>>(hidb, wkt, bk, kb, 0);
  k_gemm<<<dim3(8, 32), 256, 0, stream>>>(hidb, wvt, bv, vtb, 1);

  k_attn<<<1024, 256, 0, stream>>>(qb, kb, vtb, distb, mask, out);
}